// Round 1
// baseline (950.601 us; speedup 1.0000x reference)
//
#include <hip/hip_runtime.h>

typedef __attribute__((ext_vector_type(8))) short short8;
typedef __attribute__((ext_vector_type(4))) float floatx4;

#define D_   1024
#define L_   4096
#define B_   4
#define T_   16384
#define NCH  32     // scan chunks per sequence
#define CHL  128    // scan chunk length

__device__ __forceinline__ ushort f2bf(float f) {
  unsigned u = __float_as_uint(f);
  u += 0x7fffu + ((u >> 16) & 1u);   // round-to-nearest-even
  return (ushort)(u >> 16);
}

// ---------------- weight fp32 -> bf16 ----------------
__global__ __launch_bounds__(256) void cvt_bf(const float* __restrict__ s,
                                              ushort* __restrict__ d, int n4) {
  int i = blockIdx.x * 256 + threadIdx.x;
  if (i >= n4) return;
  float4 v = ((const float4*)s)[i];
  ushort4 o;
  o.x = f2bf(v.x); o.y = f2bf(v.y); o.z = f2bf(v.z); o.w = f2bf(v.w);
  ((ushort4*)d)[i] = o;
}

// ---------------- rmsnorm inverse-norm reduce (per token) ----------------
// inv[t] = sqrt(D) / max(||x_t||, 1e-12)
__global__ __launch_bounds__(256) void rms_reduce(const float* __restrict__ x,
                                                  float* __restrict__ inv) {
  int t = blockIdx.x;
  float4 v = ((const float4*)(x + (size_t)t * D_))[threadIdx.x];
  float s = v.x * v.x + v.y * v.y + v.z * v.z + v.w * v.w;
#pragma unroll
  for (int off = 32; off > 0; off >>= 1) s += __shfl_xor(s, off, 64);
  __shared__ float red[4];
  if ((threadIdx.x & 63) == 0) red[threadIdx.x >> 6] = s;
  __syncthreads();
  if (threadIdx.x == 0)
    inv[t] = 32.0f / fmaxf(sqrtf(red[0] + red[1] + red[2] + red[3]), 1e-12f);
}

// ---------------- fused rmsnorm-scale + causal depthwise conv (K=3) ----------------
// y[t,d] = (g[d]+1) * (w2[d]*xn[t,d] + w1[d]*xn[t-1,d] + w0[d]*xn[t-2,d]) + b[d]
// where xn[t,d] = x[t,d]*inv[t]  (inv already includes sqrt(D))
__global__ __launch_bounds__(256) void dwconv_k(const float* __restrict__ x,
                                                const float* __restrict__ inv,
                                                const float* __restrict__ wdw,
                                                const float* __restrict__ bdw,
                                                const float* __restrict__ gm,
                                                ushort* __restrict__ y) {
  int t = blockIdx.x;
  int c4 = threadIdx.x << 2;
  int l = t & (L_ - 1);
  const float* p0 = x + (size_t)t * D_ + c4;
  float i0 = inv[t], i1 = 0.f, i2 = 0.f;
  float4 v0 = *(const float4*)p0;
  float4 v1 = {0.f, 0.f, 0.f, 0.f}, v2 = {0.f, 0.f, 0.f, 0.f};
  if (l >= 1) { v1 = *(const float4*)(p0 - D_);     i1 = inv[t - 1]; }
  if (l >= 2) { v2 = *(const float4*)(p0 - 2 * D_); i2 = inv[t - 2]; }
  float a0[4] = {v0.x, v0.y, v0.z, v0.w};
  float a1[4] = {v1.x, v1.y, v1.z, v1.w};
  float a2[4] = {v2.x, v2.y, v2.z, v2.w};
  ushort r[4];
#pragma unroll
  for (int j = 0; j < 4; ++j) {
    int d = c4 + j;
    float w0 = wdw[d * 3 + 0], w1 = wdw[d * 3 + 1], w2 = wdw[d * 3 + 2];
    float s = w2 * a0[j] * i0 + w1 * a1[j] * i1 + w0 * a2[j] * i2;
    s = s * (gm[d] + 1.0f) + bdw[d];
    r[j] = f2bf(s);
  }
  ushort4 o; o.x = r[0]; o.y = r[1]; o.z = r[2]; o.w = r[3];
  *(ushort4*)(y + (size_t)t * D_ + c4) = o;
}

// ---------------- rmsnorm scale-out to bf16 ----------------
__global__ __launch_bounds__(256) void scale_w(const float* __restrict__ x,
                                               const float* __restrict__ inv,
                                               const float* __restrict__ g,
                                               ushort* __restrict__ z) {
  int idx = blockIdx.x * 256 + threadIdx.x;
  int t = idx >> 8;
  int c4 = (idx & 255) << 2;
  float iv = inv[t];
  float4 v = *(const float4*)(x + (size_t)t * D_ + c4);
  float4 gg = *(const float4*)(g + c4);
  ushort4 o;
  o.x = f2bf(v.x * iv * (gg.x + 1.f));
  o.y = f2bf(v.y * iv * (gg.y + 1.f));
  o.z = f2bf(v.z * iv * (gg.z + 1.f));
  o.w = f2bf(v.w * iv * (gg.w + 1.f));
  *(ushort4*)(z + (size_t)idx * 4) = o;
}

// ---------------- bf16 MFMA GEMM: C = A @ W^T (+bias)(+resid)(gelu) ----------------
// A: [M][K] bf16 row-major, W: [N][K] bf16 row-major.
// MODE 0: outF = acc + bias + resid (fp32). MODE 1: outF = acc (fp32).
// MODE 2: outB = bf16(gelu_exact(acc + bias)).
#define BM 128
#define BN 128
#define BK 32
#define LDA 56   // bf16 elems per LDS row: 32 + 24 pad; 112B = 7*16B (keeps b128 aligned, 2-way max conflict)

template <int MODE>
__global__ __launch_bounds__(256, 2) void gemm_k(
    const ushort* __restrict__ A, const ushort* __restrict__ W,
    const float* __restrict__ bias, const float* __restrict__ resid,
    float* __restrict__ outF, ushort* __restrict__ outB, int M, int N, int K) {
  __shared__ ushort lA[BM * LDA];
  __shared__ ushort lB[BN * LDA];
  int tid = threadIdx.x;
  int bm = blockIdx.y * BM;
  int bn = blockIdx.x * BN;
  int wave = tid >> 6, lane = tid & 63;
  int wm = (wave & 1) << 6, wn = (wave >> 1) << 6;
  int mA = tid >> 2, kc = (tid & 3) << 3;          // staging: 16B chunk per thread, x2
  const ushort* pa0 = A + (size_t)(bm + mA) * K + kc;
  const ushort* pa1 = A + (size_t)(bm + 64 + mA) * K + kc;
  const ushort* pb0 = W + (size_t)(bn + mA) * K + kc;
  const ushort* pb1 = W + (size_t)(bn + 64 + mA) * K + kc;
  int wA0 = mA * LDA + kc, wA1 = (64 + mA) * LDA + kc;
  int fr = lane & 15, fq = lane >> 4;

  floatx4 acc[4][4];
#pragma unroll
  for (int i = 0; i < 4; ++i)
#pragma unroll
    for (int j = 0; j < 4; ++j) acc[i][j] = {0.f, 0.f, 0.f, 0.f};

  for (int k0 = 0; k0 < K; k0 += BK) {
    uint4 ra0 = *(const uint4*)(pa0 + k0);
    uint4 ra1 = *(const uint4*)(pa1 + k0);
    uint4 rb0 = *(const uint4*)(pb0 + k0);
    uint4 rb1 = *(const uint4*)(pb1 + k0);
    __syncthreads();
    *(uint4*)(lA + wA0) = ra0;
    *(uint4*)(lA + wA1) = ra1;
    *(uint4*)(lB + wA0) = rb0;
    *(uint4*)(lB + wA1) = rb1;
    __syncthreads();
    short8 af[4], bfr[4];
#pragma unroll
    for (int i = 0; i < 4; ++i)
      af[i] = *(const short8*)(lA + (wm + i * 16 + fr) * LDA + fq * 8);
#pragma unroll
    for (int j = 0; j < 4; ++j)
      bfr[j] = *(const short8*)(lB + (wn + j * 16 + fr) * LDA + fq * 8);
#pragma unroll
    for (int i = 0; i < 4; ++i)
#pragma unroll
      for (int j = 0; j < 4; ++j)
        acc[i][j] = __builtin_amdgcn_mfma_f32_16x16x32_bf16(af[i], bfr[j], acc[i][j], 0, 0, 0);
  }

#pragma unroll
  for (int i = 0; i < 4; ++i) {
#pragma unroll
    for (int j = 0; j < 4; ++j) {
      int colg = bn + wn + j * 16 + fr;
      float bv = (MODE == 1) ? 0.f : bias[colg];
#pragma unroll
      for (int r = 0; r < 4; ++r) {
        int rowg = bm + wm + i * 16 + fq * 4 + r;
        size_t idx = (size_t)rowg * N + colg;
        float v = acc[i][j][r];
        if (MODE == 0) {
          outF[idx] = v + bv + resid[idx];
        } else if (MODE == 1) {
          outF[idx] = v;
        } else {
          v += bv;
          v = 0.5f * v * (1.0f + erff(v * 0.70710678118f));
          outB[idx] = f2bf(v);
        }
      }
    }
  }
}

// ---------------- minGRU linear-space chunked scan ----------------
// h_t = a_t h_{t-1} + b_t ; a = sigmoid(-gate), b = sigmoid(gate)*g(hidden)
__device__ __forceinline__ void gates(float hid, float gt, float& a, float& bv) {
  a = 1.f / (1.f + __expf(gt));             // sigmoid(-gt)
  float sg = 1.f / (1.f + __expf(-gt));     // sigmoid(gt)
  float g = (hid >= 0.f) ? (hid + 0.5f) : (1.f / (1.f + __expf(-hid)));
  bv = sg * g;
}

__global__ __launch_bounds__(256) void scan_p1(const float* __restrict__ hg,
                                               float* __restrict__ Ag,
                                               float* __restrict__ Bg) {
  int blk = blockIdx.x;
  int dt = blk & 3, ch = (blk >> 2) & 31, b = blk >> 7;
  int d = (dt << 8) + threadIdx.x;
  const float* p = hg + (size_t)(b * L_ + ch * CHL) * 2048 + d;
  float A = 1.f, Bv = 0.f;
  for (int s = 0; s < CHL; ++s) {
    float hid = p[0], gt = p[1024];
    p += 2048;
    float a, bv; gates(hid, gt, a, bv);
    A *= a;
    Bv = fmaf(a, Bv, bv);
  }
  size_t o = (size_t)((b * NCH + ch) * D_) + d;
  Ag[o] = A; Bg[o] = Bv;
}

__global__ __launch_bounds__(256) void scan_p2(const float* __restrict__ Ag,
                                               const float* __restrict__ Bg,
                                               float* __restrict__ Pre) {
  int dt = blockIdx.x & 3, b = blockIdx.x >> 2;
  int d = (dt << 8) + threadIdx.x;
  float h = 0.f;
  for (int c = 0; c < NCH; ++c) {
    size_t i = (size_t)((b * NCH + c) * D_) + d;
    Pre[i] = h;
    h = fmaf(Ag[i], h, Bg[i]);
  }
}

// pass 3: replay chunk with true prefix; x2 = h + x1 written in-place into xio;
// last token's h goes to next_hidden.
__global__ __launch_bounds__(256) void scan_p3(const float* __restrict__ hg,
                                               const float* __restrict__ Pre,
                                               float* __restrict__ xio,
                                               float* __restrict__ nh) {
  int blk = blockIdx.x;
  int dt = blk & 3, ch = (blk >> 2) & 31, b = blk >> 7;
  int d = (dt << 8) + threadIdx.x;
  const float* p = hg + (size_t)(b * L_ + ch * CHL) * 2048 + d;
  float* q = xio + (size_t)(b * L_ + ch * CHL) * D_ + d;
  float h = Pre[(size_t)((b * NCH + ch) * D_) + d];
  for (int s = 0; s < CHL; ++s) {
    float hid = p[0], gt = p[1024];
    p += 2048;
    float a, bv; gates(hid, gt, a, bv);
    h = fmaf(a, h, bv);
    *q = h + *q;
    q += D_;
  }
  if (ch == NCH - 1) nh[(b << 10) + d] = h;
}

// ---------------- launcher ----------------
extern "C" void kernel_launch(void* const* d_in, const int* in_sizes, int n_in,
                              void* d_out, int out_size, void* d_ws, size_t ws_size,
                              hipStream_t stream) {
  const float* x   = (const float*)d_in[0];
  const float* cdw = (const float*)d_in[1];
  const float* cdb = (const float*)d_in[2];
  const float* cpw = (const float*)d_in[3];
  const float* cpb = (const float*)d_in[4];
  const float* cng = (const float*)d_in[5];
  const float* gng = (const float*)d_in[6];
  const float* gw  = (const float*)d_in[7];
  const float* fng = (const float*)d_in[8];
  const float* fw1 = (const float*)d_in[9];
  const float* fb1 = (const float*)d_in[10];
  const float* fw2 = (const float*)d_in[11];
  const float* fb2 = (const float*)d_in[12];
  float* out = (float*)d_out;
  char* ws = (char*)d_ws;

  // workspace layout (bytes, all 256-aligned); total ~184 MiB
  ushort* wpw_b = (ushort*)(ws + 0);          //  2 MiB
  ushort* wgr_b = (ushort*)(ws + 2097152);    //  4 MiB
  ushort* wf1_b = (ushort*)(ws + 6291456);    //  8 MiB
  ushort* wf2_b = (ushort*)(ws + 14680064);   //  8 MiB
  float*  inv   = (float*) (ws + 23068672);   // 64 KiB
  float*  Ag    = (float*) (ws + 23134208);   // 512 KiB
  float*  Bg    = (float*) (ws + 23658496);   // 512 KiB
  float*  Pre   = (float*) (ws + 24182784);   // 512 KiB
  ushort* zbuf  = (ushort*)(ws + 24707072);   // 32 MiB (y / z1 / z2, reused)
  float*  hg    = (float*) (ws + 58261504);   // 128 MiB fp32 [T][2048]
  ushort* h1    = (ushort*)(ws + 58261504);   // 128 MiB bf16 [T][4096] (overlays hg; hg dead by then)
  float*  nh    = out + (size_t)T_ * D_;      // next_hidden tail of d_out

  // weights -> bf16
  cvt_bf<<<dim3(1024), 256, 0, stream>>>(cpw, wpw_b, 262144);
  cvt_bf<<<dim3(2048), 256, 0, stream>>>(gw,  wgr_b, 524288);
  cvt_bf<<<dim3(4096), 256, 0, stream>>>(fw1, wf1_b, 1048576);
  cvt_bf<<<dim3(4096), 256, 0, stream>>>(fw2, wf2_b, 1048576);

  // stage 1: rmsnorm + causal dwconv -> y (bf16), then x1 = y@Wpw^T + b + x -> d_out
  rms_reduce<<<dim3(T_), 256, 0, stream>>>(x, inv);
  dwconv_k<<<dim3(T_), 256, 0, stream>>>(x, inv, cdw, cdb, cng, zbuf);
  gemm_k<0><<<dim3(8, 128), 256, 0, stream>>>(zbuf, wpw_b, cpb, x, out, nullptr, T_, 1024, 1024);

  // stage 2: rmsnorm(x1) -> z1; hg = z1 @ Wgru^T; chunked scan; x2 = h + x1 (in-place d_out)
  rms_reduce<<<dim3(T_), 256, 0, stream>>>(out, inv);
  scale_w<<<dim3(T_), 256, 0, stream>>>(out, inv, gng, zbuf);
  gemm_k<1><<<dim3(16, 128), 256, 0, stream>>>(zbuf, wgr_b, nullptr, nullptr, hg, nullptr, T_, 2048, 1024);
  scan_p1<<<dim3(512), 256, 0, stream>>>(hg, Ag, Bg);
  scan_p2<<<dim3(16), 256, 0, stream>>>(Ag, Bg, Pre);
  scan_p3<<<dim3(512), 256, 0, stream>>>(hg, Pre, out, nh);

  // stage 3: rmsnorm(x2) -> z2; h1 = gelu(z2@W1^T + b1) bf16; out = h1@W2^T + b2 + x2
  rms_reduce<<<dim3(T_), 256, 0, stream>>>(out, inv);
  scale_w<<<dim3(T_), 256, 0, stream>>>(out, inv, fng, zbuf);
  gemm_k<2><<<dim3(32, 128), 256, 0, stream>>>(zbuf, wf1_b, fb1, nullptr, nullptr, h1, T_, 4096, 1024);
  gemm_k<0><<<dim3(8, 128), 256, 0, stream>>>(h1, wf2_b, fb2, out, out, nullptr, T_, 1024, 4096);
}

// Round 2
// 886.170 us; speedup vs baseline: 1.0727x; 1.0727x over previous
//
#include <hip/hip_runtime.h>

typedef __attribute__((ext_vector_type(8))) short short8;
typedef __attribute__((ext_vector_type(4))) float floatx4;

#define D_   1024
#define L_   4096
#define B_   4
#define T_   16384
#define NCH  32     // scan chunks per sequence
#define CHL  128    // scan chunk length

__device__ __forceinline__ ushort f2bf(float f) {
  unsigned u = __float_as_uint(f);
  u += 0x7fffu + ((u >> 16) & 1u);   // round-to-nearest-even
  return (ushort)(u >> 16);
}
__device__ __forceinline__ float bf2f(ushort u) {
  return __uint_as_float(((unsigned)u) << 16);
}

// async global->LDS, 16B per lane. LDS dest MUST be wave-uniform base + lane*16.
__device__ __forceinline__ void gl2lds(const ushort* g, ushort* l) {
  __builtin_amdgcn_global_load_lds(
      (const __attribute__((address_space(1))) unsigned int*)g,
      (__attribute__((address_space(3))) unsigned int*)l, 16, 0, 0);
}

// ---------------- weight fp32 -> bf16 ----------------
__global__ __launch_bounds__(256) void cvt_bf(const float* __restrict__ s,
                                              ushort* __restrict__ d, int n4) {
  int i = blockIdx.x * 256 + threadIdx.x;
  if (i >= n4) return;
  float4 v = ((const float4*)s)[i];
  ushort4 o;
  o.x = f2bf(v.x); o.y = f2bf(v.y); o.z = f2bf(v.z); o.w = f2bf(v.w);
  ((ushort4*)d)[i] = o;
}

// ---------------- rmsnorm inverse-norm reduce (per token; stage 1 only) ----------------
__global__ __launch_bounds__(256) void rms_reduce(const float* __restrict__ x,
                                                  float* __restrict__ inv) {
  int t = blockIdx.x;
  float4 v = ((const float4*)(x + (size_t)t * D_))[threadIdx.x];
  float s = v.x * v.x + v.y * v.y + v.z * v.z + v.w * v.w;
#pragma unroll
  for (int off = 32; off > 0; off >>= 1) s += __shfl_xor(s, off, 64);
  __shared__ float red[4];
  if ((threadIdx.x & 63) == 0) red[threadIdx.x >> 6] = s;
  __syncthreads();
  if (threadIdx.x == 0)
    inv[t] = 32.0f / fmaxf(sqrtf(red[0] + red[1] + red[2] + red[3]), 1e-12f);
}

// ---------------- fused rmsnorm + gamma-scale -> bf16 (stages 2,3) ----------------
__global__ __launch_bounds__(256) void rms_scale(const float* __restrict__ x,
                                                 const float* __restrict__ g,
                                                 ushort* __restrict__ z) {
  int t = blockIdx.x;
  float4 v = ((const float4*)(x + (size_t)t * D_))[threadIdx.x];
  float s = v.x * v.x + v.y * v.y + v.z * v.z + v.w * v.w;
#pragma unroll
  for (int off = 32; off > 0; off >>= 1) s += __shfl_xor(s, off, 64);
  __shared__ float red[4];
  if ((threadIdx.x & 63) == 0) red[threadIdx.x >> 6] = s;
  __syncthreads();
  float iv = 32.0f / fmaxf(sqrtf(red[0] + red[1] + red[2] + red[3]), 1e-12f);
  float4 gg = ((const float4*)g)[threadIdx.x];
  ushort4 o;
  o.x = f2bf(v.x * iv * (gg.x + 1.f));
  o.y = f2bf(v.y * iv * (gg.y + 1.f));
  o.z = f2bf(v.z * iv * (gg.z + 1.f));
  o.w = f2bf(v.w * iv * (gg.w + 1.f));
  ((ushort4*)(z + (size_t)t * D_))[threadIdx.x] = o;
}

// ---------------- fused rmsnorm-scale + causal depthwise conv (K=3) ----------------
__global__ __launch_bounds__(256) void dwconv_k(const float* __restrict__ x,
                                                const float* __restrict__ inv,
                                                const float* __restrict__ wdw,
                                                const float* __restrict__ bdw,
                                                const float* __restrict__ gm,
                                                ushort* __restrict__ y) {
  int t = blockIdx.x;
  int c4 = threadIdx.x << 2;
  int l = t & (L_ - 1);
  const float* p0 = x + (size_t)t * D_ + c4;
  float i0 = inv[t], i1 = 0.f, i2 = 0.f;
  float4 v0 = *(const float4*)p0;
  float4 v1 = {0.f, 0.f, 0.f, 0.f}, v2 = {0.f, 0.f, 0.f, 0.f};
  if (l >= 1) { v1 = *(const float4*)(p0 - D_);     i1 = inv[t - 1]; }
  if (l >= 2) { v2 = *(const float4*)(p0 - 2 * D_); i2 = inv[t - 2]; }
  float a0[4] = {v0.x, v0.y, v0.z, v0.w};
  float a1[4] = {v1.x, v1.y, v1.z, v1.w};
  float a2[4] = {v2.x, v2.y, v2.z, v2.w};
  ushort r[4];
#pragma unroll
  for (int j = 0; j < 4; ++j) {
    int d = c4 + j;
    float w0 = wdw[d * 3 + 0], w1 = wdw[d * 3 + 1], w2 = wdw[d * 3 + 2];
    float s = w2 * a0[j] * i0 + w1 * a1[j] * i1 + w0 * a2[j] * i2;
    s = s * (gm[d] + 1.0f) + bdw[d];
    r[j] = f2bf(s);
  }
  ushort4 o; o.x = r[0]; o.y = r[1]; o.z = r[2]; o.w = r[3];
  *(ushort4*)(y + (size_t)t * D_ + c4) = o;
}

// ---------------- bf16 MFMA GEMM (m97 pattern: global_load_lds staging) ----------------
// A: [M][K] bf16 row-major, W: [N][K] bf16 row-major. C = A @ W^T.
// MODE 0: outF = acc + bias + resid (fp32). MODE 2: outB = bf16(gelu(acc+bias)).
// MODE 3: outB = bf16(acc).
template <int MODE>
__global__ __launch_bounds__(256, 2) void gemm_k(
    const ushort* __restrict__ A, const ushort* __restrict__ W,
    const float* __restrict__ bias, const float* __restrict__ resid,
    float* __restrict__ outF, ushort* __restrict__ outB, int M, int N, int K) {
  // unpadded [128][32] bf16 tiles: global_load_lds requires lane-order-contiguous dest
  __shared__ ushort lA[128 * 32];
  __shared__ ushort lB[128 * 32];
  int tid = threadIdx.x;
  int bm = blockIdx.y * 128;
  int bn = blockIdx.x * 128;
  int wave = tid >> 6, lane = tid & 63;
  int wm = (wave & 1) << 6, wn = (wave >> 1) << 6;
  int row = tid >> 2, kc = (tid & 3) << 3;   // each thread DMAs 16B; 256 thr = 64 rows
  const ushort* pa0 = A + (size_t)(bm + row) * K + kc;
  const ushort* pa1 = pa0 + (size_t)64 * K;
  const ushort* pb0 = W + (size_t)(bn + row) * K + kc;
  const ushort* pb1 = pb0 + (size_t)64 * K;
  ushort* dA0 = lA + tid * 8;           // == (row*32 + kc), lane-contiguous
  ushort* dA1 = dA0 + 64 * 32;
  ushort* dB0 = lB + tid * 8;
  ushort* dB1 = dB0 + 64 * 32;
  int fr = lane & 15, fq = lane >> 4;

  floatx4 acc[4][4];
#pragma unroll
  for (int i = 0; i < 4; ++i)
#pragma unroll
    for (int j = 0; j < 4; ++j) acc[i][j] = {0.f, 0.f, 0.f, 0.f};

  for (int k0 = 0; k0 < K; k0 += 32) {
    __syncthreads();                    // previous tile fully consumed
    gl2lds(pa0 + k0, dA0);
    gl2lds(pa1 + k0, dA1);
    gl2lds(pb0 + k0, dB0);
    gl2lds(pb1 + k0, dB1);
    __syncthreads();                    // vmcnt(0) drained -> tile ready
    short8 af[4], bfr[4];
#pragma unroll
    for (int i = 0; i < 4; ++i)
      af[i] = *(const short8*)(lA + (wm + i * 16 + fr) * 32 + fq * 8);
#pragma unroll
    for (int j = 0; j < 4; ++j)
      bfr[j] = *(const short8*)(lB + (wn + j * 16 + fr) * 32 + fq * 8);
#pragma unroll
    for (int i = 0; i < 4; ++i)
#pragma unroll
      for (int j = 0; j < 4; ++j)
        acc[i][j] = __builtin_amdgcn_mfma_f32_16x16x32_bf16(af[i], bfr[j], acc[i][j], 0, 0, 0);
  }

#pragma unroll
  for (int i = 0; i < 4; ++i) {
#pragma unroll
    for (int j = 0; j < 4; ++j) {
      int colg = bn + wn + j * 16 + fr;
      float bv = (MODE == 3) ? 0.f : bias[colg];
#pragma unroll
      for (int r = 0; r < 4; ++r) {
        int rowg = bm + wm + i * 16 + fq * 4 + r;
        size_t idx = (size_t)rowg * N + colg;
        float v = acc[i][j][r];
        if (MODE == 0) {
          outF[idx] = v + bv + resid[idx];
        } else if (MODE == 2) {
          v += bv;
          v = 0.5f * v * (1.0f + erff(v * 0.70710678118f));
          outB[idx] = f2bf(v);
        } else {
          outB[idx] = f2bf(v);
        }
      }
    }
  }
}

// ---------------- minGRU linear-space chunked scan (bf16 hg) ----------------
// h_t = a_t h_{t-1} + b_t ; a = sigmoid(-gate), b = sigmoid(gate)*g(hidden)
__device__ __forceinline__ void gates(float hid, float gt, float& a, float& bv) {
  a = 1.f / (1.f + __expf(gt));             // sigmoid(-gt)
  float sg = 1.f / (1.f + __expf(-gt));     // sigmoid(gt)
  float g = (hid >= 0.f) ? (hid + 0.5f) : (1.f / (1.f + __expf(-hid)));
  bv = sg * g;
}

__global__ __launch_bounds__(256) void scan_p1(const ushort* __restrict__ hg,
                                               float* __restrict__ Ag,
                                               float* __restrict__ Bg) {
  int blk = blockIdx.x;
  int dt = blk & 3, ch = (blk >> 2) & 31, b = blk >> 7;
  int d = (dt << 8) + threadIdx.x;
  const ushort* p = hg + (size_t)(b * L_ + ch * CHL) * 2048 + d;
  float A = 1.f, Bv = 0.f;
  for (int s = 0; s < CHL; ++s) {
    float hid = bf2f(p[0]), gt = bf2f(p[1024]);
    p += 2048;
    float a, bv; gates(hid, gt, a, bv);
    A *= a;
    Bv = fmaf(a, Bv, bv);
  }
  size_t o = (size_t)((b * NCH + ch) * D_) + d;
  Ag[o] = A; Bg[o] = Bv;
}

__global__ __launch_bounds__(256) void scan_p2(const float* __restrict__ Ag,
                                               const float* __restrict__ Bg,
                                               float* __restrict__ Pre) {
  int dt = blockIdx.x & 3, b = blockIdx.x >> 2;
  int d = (dt << 8) + threadIdx.x;
  float h = 0.f;
  for (int c = 0; c < NCH; ++c) {
    size_t i = (size_t)((b * NCH + c) * D_) + d;
    Pre[i] = h;
    h = fmaf(Ag[i], h, Bg[i]);
  }
}

__global__ __launch_bounds__(256) void scan_p3(const ushort* __restrict__ hg,
                                               const float* __restrict__ Pre,
                                               float* __restrict__ xio,
                                               float* __restrict__ nh) {
  int blk = blockIdx.x;
  int dt = blk & 3, ch = (blk >> 2) & 31, b = blk >> 7;
  int d = (dt << 8) + threadIdx.x;
  const ushort* p = hg + (size_t)(b * L_ + ch * CHL) * 2048 + d;
  float* q = xio + (size_t)(b * L_ + ch * CHL) * D_ + d;
  float h = Pre[(size_t)((b * NCH + ch) * D_) + d];
  for (int s = 0; s < CHL; ++s) {
    float hid = bf2f(p[0]), gt = bf2f(p[1024]);
    p += 2048;
    float a, bv; gates(hid, gt, a, bv);
    h = fmaf(a, h, bv);
    *q = h + *q;
    q += D_;
  }
  if (ch == NCH - 1) nh[(b << 10) + d] = h;
}

// ---------------- launcher ----------------
extern "C" void kernel_launch(void* const* d_in, const int* in_sizes, int n_in,
                              void* d_out, int out_size, void* d_ws, size_t ws_size,
                              hipStream_t stream) {
  const float* x   = (const float*)d_in[0];
  const float* cdw = (const float*)d_in[1];
  const float* cdb = (const float*)d_in[2];
  const float* cpw = (const float*)d_in[3];
  const float* cpb = (const float*)d_in[4];
  const float* cng = (const float*)d_in[5];
  const float* gng = (const float*)d_in[6];
  const float* gw  = (const float*)d_in[7];
  const float* fng = (const float*)d_in[8];
  const float* fw1 = (const float*)d_in[9];
  const float* fb1 = (const float*)d_in[10];
  const float* fw2 = (const float*)d_in[11];
  const float* fb2 = (const float*)d_in[12];
  float* out = (float*)d_out;
  char* ws = (char*)d_ws;

  // workspace layout (bytes)
  ushort* wpw_b = (ushort*)(ws + 0);          //  2 MiB
  ushort* wgr_b = (ushort*)(ws + 2097152);    //  4 MiB
  ushort* wf1_b = (ushort*)(ws + 6291456);    //  8 MiB
  ushort* wf2_b = (ushort*)(ws + 14680064);   //  8 MiB
  float*  inv   = (float*) (ws + 23068672);   // 64 KiB
  float*  Ag    = (float*) (ws + 23134208);   // 512 KiB
  float*  Bg    = (float*) (ws + 23658496);   // 512 KiB
  float*  Pre   = (float*) (ws + 24182784);   // 512 KiB
  ushort* zbuf  = (ushort*)(ws + 24707072);   // 32 MiB (y / z1 / z2, reused)
  ushort* hg    = (ushort*)(ws + 58261504);   // 64 MiB bf16 [T][2048]
  ushort* h1    = (ushort*)(ws + 58261504);   // 128 MiB bf16 [T][4096] (overlays hg; hg dead)
  float*  nh    = out + (size_t)T_ * D_;      // next_hidden tail of d_out

  // weights -> bf16
  cvt_bf<<<dim3(1024), 256, 0, stream>>>(cpw, wpw_b, 262144);
  cvt_bf<<<dim3(2048), 256, 0, stream>>>(gw,  wgr_b, 524288);
  cvt_bf<<<dim3(4096), 256, 0, stream>>>(fw1, wf1_b, 1048576);
  cvt_bf<<<dim3(4096), 256, 0, stream>>>(fw2, wf2_b, 1048576);

  // stage 1: rmsnorm + causal dwconv -> y (bf16); x1 = y@Wpw^T + b + x -> d_out
  rms_reduce<<<dim3(T_), 256, 0, stream>>>(x, inv);
  dwconv_k<<<dim3(T_), 256, 0, stream>>>(x, inv, cdw, cdb, cng, zbuf);
  gemm_k<0><<<dim3(8, 128), 256, 0, stream>>>(zbuf, wpw_b, cpb, x, out, nullptr, T_, 1024, 1024);

  // stage 2: z1 = rmsnorm(x1)*g (bf16); hg = z1 @ Wgru^T (bf16); scan; x2 = h + x1 in-place
  rms_scale<<<dim3(T_), 256, 0, stream>>>(out, gng, zbuf);
  gemm_k<3><<<dim3(16, 128), 256, 0, stream>>>(zbuf, wgr_b, nullptr, nullptr, nullptr, hg, T_, 2048, 1024);
  scan_p1<<<dim3(512), 256, 0, stream>>>(hg, Ag, Bg);
  scan_p2<<<dim3(16), 256, 0, stream>>>(Ag, Bg, Pre);
  scan_p3<<<dim3(512), 256, 0, stream>>>(hg, Pre, out, nh);

  // stage 3: z2 = rmsnorm(x2)*g (bf16); h1 = gelu(z2@W1^T + b1) bf16; out = h1@W2^T + b2 + x2
  rms_scale<<<dim3(T_), 256, 0, stream>>>(out, fng, zbuf);
  gemm_k<2><<<dim3(32, 128), 256, 0, stream>>>(zbuf, wf1_b, fb1, nullptr, nullptr, h1, T_, 4096, 1024);
  gemm_k<0><<<dim3(8, 128), 256, 0, stream>>>(h1, wf2_b, fb2, out, out, nullptr, T_, 1024, 4096);
}

// Round 3
// 838.045 us; speedup vs baseline: 1.1343x; 1.0574x over previous
//
#include <hip/hip_runtime.h>

typedef __attribute__((ext_vector_type(8))) short short8;
typedef __attribute__((ext_vector_type(4))) float floatx4;

#define D_   1024
#define L_   4096
#define B_   4
#define T_   16384
#define NCH  32     // scan chunks per sequence
#define CHL  128    // scan chunk length

__device__ __forceinline__ ushort f2bf(float f) {
  unsigned u = __float_as_uint(f);
  u += 0x7fffu + ((u >> 16) & 1u);   // round-to-nearest-even
  return (ushort)(u >> 16);
}
__device__ __forceinline__ float bf2f(ushort u) {
  return __uint_as_float(((unsigned)u) << 16);
}

// async global->LDS, 16B per lane. LDS dest MUST be wave-uniform base + lane*16.
__device__ __forceinline__ void gl2lds(const ushort* g, ushort* l) {
  __builtin_amdgcn_global_load_lds(
      (const __attribute__((address_space(1))) unsigned int*)g,
      (__attribute__((address_space(3))) unsigned int*)l, 16, 0, 0);
}

// ---------------- weight fp32 -> bf16 ----------------
__global__ __launch_bounds__(256) void cvt_bf(const float* __restrict__ s,
                                              ushort* __restrict__ d, int n4) {
  int i = blockIdx.x * 256 + threadIdx.x;
  if (i >= n4) return;
  float4 v = ((const float4*)s)[i];
  ushort4 o;
  o.x = f2bf(v.x); o.y = f2bf(v.y); o.z = f2bf(v.z); o.w = f2bf(v.w);
  ((ushort4*)d)[i] = o;
}

// ---------------- rmsnorm inverse-norm reduce (per token; stage 1 only) ----------------
__global__ __launch_bounds__(256) void rms_reduce(const float* __restrict__ x,
                                                  float* __restrict__ inv) {
  int t = blockIdx.x;
  float4 v = ((const float4*)(x + (size_t)t * D_))[threadIdx.x];
  float s = v.x * v.x + v.y * v.y + v.z * v.z + v.w * v.w;
#pragma unroll
  for (int off = 32; off > 0; off >>= 1) s += __shfl_xor(s, off, 64);
  __shared__ float red[4];
  if ((threadIdx.x & 63) == 0) red[threadIdx.x >> 6] = s;
  __syncthreads();
  if (threadIdx.x == 0)
    inv[t] = 32.0f / fmaxf(sqrtf(red[0] + red[1] + red[2] + red[3]), 1e-12f);
}

// ---------------- fused rmsnorm + gamma-scale -> bf16 (stages 2,3) ----------------
__global__ __launch_bounds__(256) void rms_scale(const float* __restrict__ x,
                                                 const float* __restrict__ g,
                                                 ushort* __restrict__ z) {
  int t = blockIdx.x;
  float4 v = ((const float4*)(x + (size_t)t * D_))[threadIdx.x];
  float s = v.x * v.x + v.y * v.y + v.z * v.z + v.w * v.w;
#pragma unroll
  for (int off = 32; off > 0; off >>= 1) s += __shfl_xor(s, off, 64);
  __shared__ float red[4];
  if ((threadIdx.x & 63) == 0) red[threadIdx.x >> 6] = s;
  __syncthreads();
  float iv = 32.0f / fmaxf(sqrtf(red[0] + red[1] + red[2] + red[3]), 1e-12f);
  float4 gg = ((const float4*)g)[threadIdx.x];
  ushort4 o;
  o.x = f2bf(v.x * iv * (gg.x + 1.f));
  o.y = f2bf(v.y * iv * (gg.y + 1.f));
  o.z = f2bf(v.z * iv * (gg.z + 1.f));
  o.w = f2bf(v.w * iv * (gg.w + 1.f));
  ((ushort4*)(z + (size_t)t * D_))[threadIdx.x] = o;
}

// ---------------- fused rmsnorm-scale + causal depthwise conv (K=3) ----------------
__global__ __launch_bounds__(256) void dwconv_k(const float* __restrict__ x,
                                                const float* __restrict__ inv,
                                                const float* __restrict__ wdw,
                                                const float* __restrict__ bdw,
                                                const float* __restrict__ gm,
                                                ushort* __restrict__ y) {
  int t = blockIdx.x;
  int c4 = threadIdx.x << 2;
  int l = t & (L_ - 1);
  const float* p0 = x + (size_t)t * D_ + c4;
  float i0 = inv[t], i1 = 0.f, i2 = 0.f;
  float4 v0 = *(const float4*)p0;
  float4 v1 = {0.f, 0.f, 0.f, 0.f}, v2 = {0.f, 0.f, 0.f, 0.f};
  if (l >= 1) { v1 = *(const float4*)(p0 - D_);     i1 = inv[t - 1]; }
  if (l >= 2) { v2 = *(const float4*)(p0 - 2 * D_); i2 = inv[t - 2]; }
  float a0[4] = {v0.x, v0.y, v0.z, v0.w};
  float a1[4] = {v1.x, v1.y, v1.z, v1.w};
  float a2[4] = {v2.x, v2.y, v2.z, v2.w};
  ushort r[4];
#pragma unroll
  for (int j = 0; j < 4; ++j) {
    int d = c4 + j;
    float w0 = wdw[d * 3 + 0], w1 = wdw[d * 3 + 1], w2 = wdw[d * 3 + 2];
    float s = w2 * a0[j] * i0 + w1 * a1[j] * i1 + w0 * a2[j] * i2;
    s = s * (gm[d] + 1.0f) + bdw[d];
    r[j] = f2bf(s);
  }
  ushort4 o; o.x = r[0]; o.y = r[1]; o.z = r[2]; o.w = r[3];
  *(ushort4*)(y + (size_t)t * D_ + c4) = o;
}

// ---------------- bf16 MFMA GEMM (m97 pattern + XCD-aware swizzle) ----------------
// A: [M][K] bf16 row-major, W: [N][K] bf16 row-major. C = A @ W^T.
// MODE 0: outF = acc + bias + resid (fp32). MODE 2: outB = bf16(gelu(acc+bias)).
// MODE 3: outB = bf16(acc).
// Swizzle: XCD c = lin%8 owns row-tiles [c*16, c*16+16); within an XCD the nx
// column-tiles of one row are consecutive -> A row-slice fetched once per XCD L2.
template <int MODE>
__global__ __launch_bounds__(256, 2) void gemm_k(
    const ushort* __restrict__ A, const ushort* __restrict__ W,
    const float* __restrict__ bias, const float* __restrict__ resid,
    float* __restrict__ outF, ushort* __restrict__ outB, int M, int N, int K) {
  __shared__ ushort lA[128 * 32];
  __shared__ ushort lB[128 * 32];
  int tid = threadIdx.x;

  // --- XCD-aware remap (requires gridDim.y % 8 == 0, nx a power of 2) ---
  int nx = gridDim.x;
  int lxs = 31 - __clz(nx);                // log2(nx)
  int lin = blockIdx.x + blockIdx.y * nx;  // dispatch-order linear id
  int c = lin & 7, q = lin >> 3;
  int by = (c * (gridDim.y >> 3)) + (q >> lxs);
  int bx = q & (nx - 1);
  int bm = by * 128;
  int bn = bx * 128;

  int wave = tid >> 6, lane = tid & 63;
  int wm = (wave & 1) << 6, wn = (wave >> 1) << 6;
  int row = tid >> 2, kc = (tid & 3) << 3;   // each thread DMAs 16B; 256 thr = 64 rows
  const ushort* pa0 = A + (size_t)(bm + row) * K + kc;
  const ushort* pa1 = pa0 + (size_t)64 * K;
  const ushort* pb0 = W + (size_t)(bn + row) * K + kc;
  const ushort* pb1 = pb0 + (size_t)64 * K;
  ushort* dA0 = lA + tid * 8;           // == (row*32 + kc), lane-contiguous
  ushort* dA1 = dA0 + 64 * 32;
  ushort* dB0 = lB + tid * 8;
  ushort* dB1 = dB0 + 64 * 32;
  int fr = lane & 15, fq = lane >> 4;

  floatx4 acc[4][4];
#pragma unroll
  for (int i = 0; i < 4; ++i)
#pragma unroll
    for (int j = 0; j < 4; ++j) acc[i][j] = {0.f, 0.f, 0.f, 0.f};

  for (int k0 = 0; k0 < K; k0 += 32) {
    __syncthreads();                    // previous tile fully consumed
    gl2lds(pa0 + k0, dA0);
    gl2lds(pa1 + k0, dA1);
    gl2lds(pb0 + k0, dB0);
    gl2lds(pb1 + k0, dB1);
    __syncthreads();                    // vmcnt(0) drained -> tile ready
    short8 af[4], bfr[4];
#pragma unroll
    for (int i = 0; i < 4; ++i)
      af[i] = *(const short8*)(lA + (wm + i * 16 + fr) * 32 + fq * 8);
#pragma unroll
    for (int j = 0; j < 4; ++j)
      bfr[j] = *(const short8*)(lB + (wn + j * 16 + fr) * 32 + fq * 8);
#pragma unroll
    for (int i = 0; i < 4; ++i)
#pragma unroll
      for (int j = 0; j < 4; ++j)
        acc[i][j] = __builtin_amdgcn_mfma_f32_16x16x32_bf16(af[i], bfr[j], acc[i][j], 0, 0, 0);
  }

#pragma unroll
  for (int i = 0; i < 4; ++i) {
#pragma unroll
    for (int j = 0; j < 4; ++j) {
      int colg = bn + wn + j * 16 + fr;
      float bv = (MODE == 3) ? 0.f : bias[colg];
#pragma unroll
      for (int r = 0; r < 4; ++r) {
        int rowg = bm + wm + i * 16 + fq * 4 + r;
        size_t idx = (size_t)rowg * N + colg;
        float v = acc[i][j][r];
        if (MODE == 0) {
          outF[idx] = v + bv + resid[idx];
        } else if (MODE == 2) {
          v += bv;
          v = 0.5f * v * (1.0f + erff(v * 0.70710678118f));
          outB[idx] = f2bf(v);
        } else {
          outB[idx] = f2bf(v);
        }
      }
    }
  }
}

// ---------------- minGRU linear-space chunked scan (bf16 hg) ----------------
// h_t = a_t h_{t-1} + b_t ; a = sigmoid(-gate), b = sigmoid(gate)*g(hidden)
__device__ __forceinline__ void gates(float hid, float gt, float& a, float& bv) {
  a = 1.f / (1.f + __expf(gt));             // sigmoid(-gt)
  float sg = 1.f / (1.f + __expf(-gt));     // sigmoid(gt)
  float g = (hid >= 0.f) ? (hid + 0.5f) : (1.f / (1.f + __expf(-hid)));
  bv = sg * g;
}

__global__ __launch_bounds__(256) void scan_p1(const ushort* __restrict__ hg,
                                               float* __restrict__ Ag,
                                               float* __restrict__ Bg) {
  int blk = blockIdx.x;
  int dt = blk & 3, ch = (blk >> 2) & 31, b = blk >> 7;
  int d = (dt << 8) + threadIdx.x;
  const ushort* p = hg + (size_t)(b * L_ + ch * CHL) * 2048 + d;
  float A = 1.f, Bv = 0.f;
  for (int s = 0; s < CHL; ++s) {
    float hid = bf2f(p[0]), gt = bf2f(p[1024]);
    p += 2048;
    float a, bv; gates(hid, gt, a, bv);
    A *= a;
    Bv = fmaf(a, Bv, bv);
  }
  size_t o = (size_t)((b * NCH + ch) * D_) + d;
  Ag[o] = A; Bg[o] = Bv;
}

__global__ __launch_bounds__(256) void scan_p2(const float* __restrict__ Ag,
                                               const float* __restrict__ Bg,
                                               float* __restrict__ Pre) {
  int dt = blockIdx.x & 3, b = blockIdx.x >> 2;
  int d = (dt << 8) + threadIdx.x;
  float h = 0.f;
  for (int c = 0; c < NCH; ++c) {
    size_t i = (size_t)((b * NCH + c) * D_) + d;
    Pre[i] = h;
    h = fmaf(Ag[i], h, Bg[i]);
  }
}

__global__ __launch_bounds__(256) void scan_p3(const ushort* __restrict__ hg,
                                               const float* __restrict__ Pre,
                                               float* __restrict__ xio,
                                               float* __restrict__ nh) {
  int blk = blockIdx.x;
  int dt = blk & 3, ch = (blk >> 2) & 31, b = blk >> 7;
  int d = (dt << 8) + threadIdx.x;
  const ushort* p = hg + (size_t)(b * L_ + ch * CHL) * 2048 + d;
  float* q = xio + (size_t)(b * L_ + ch * CHL) * D_ + d;
  float h = Pre[(size_t)((b * NCH + ch) * D_) + d];
  for (int s = 0; s < CHL; ++s) {
    float hid = bf2f(p[0]), gt = bf2f(p[1024]);
    p += 2048;
    float a, bv; gates(hid, gt, a, bv);
    h = fmaf(a, h, bv);
    *q = h + *q;
    q += D_;
  }
  if (ch == NCH - 1) nh[(b << 10) + d] = h;
}

// ---------------- launcher ----------------
extern "C" void kernel_launch(void* const* d_in, const int* in_sizes, int n_in,
                              void* d_out, int out_size, void* d_ws, size_t ws_size,
                              hipStream_t stream) {
  const float* x   = (const float*)d_in[0];
  const float* cdw = (const float*)d_in[1];
  const float* cdb = (const float*)d_in[2];
  const float* cpw = (const float*)d_in[3];
  const float* cpb = (const float*)d_in[4];
  const float* cng = (const float*)d_in[5];
  const float* gng = (const float*)d_in[6];
  const float* gw  = (const float*)d_in[7];
  const float* fng = (const float*)d_in[8];
  const float* fw1 = (const float*)d_in[9];
  const float* fb1 = (const float*)d_in[10];
  const float* fw2 = (const float*)d_in[11];
  const float* fb2 = (const float*)d_in[12];
  float* out = (float*)d_out;
  char* ws = (char*)d_ws;

  // workspace layout (bytes)
  ushort* wpw_b = (ushort*)(ws + 0);          //  2 MiB
  ushort* wgr_b = (ushort*)(ws + 2097152);    //  4 MiB
  ushort* wf1_b = (ushort*)(ws + 6291456);    //  8 MiB
  ushort* wf2_b = (ushort*)(ws + 14680064);   //  8 MiB
  float*  inv   = (float*) (ws + 23068672);   // 64 KiB
  float*  Ag    = (float*) (ws + 23134208);   // 512 KiB
  float*  Bg    = (float*) (ws + 23658496);   // 512 KiB
  float*  Pre   = (float*) (ws + 24182784);   // 512 KiB
  ushort* zbuf  = (ushort*)(ws + 24707072);   // 32 MiB (y / z1 / z2, reused)
  ushort* hg    = (ushort*)(ws + 58261504);   // 64 MiB bf16 [T][2048]
  ushort* h1    = (ushort*)(ws + 58261504);   // 128 MiB bf16 [T][4096] (overlays hg; hg dead)
  float*  nh    = out + (size_t)T_ * D_;      // next_hidden tail of d_out

  // weights -> bf16
  cvt_bf<<<dim3(1024), 256, 0, stream>>>(cpw, wpw_b, 262144);
  cvt_bf<<<dim3(2048), 256, 0, stream>>>(gw,  wgr_b, 524288);
  cvt_bf<<<dim3(4096), 256, 0, stream>>>(fw1, wf1_b, 1048576);
  cvt_bf<<<dim3(4096), 256, 0, stream>>>(fw2, wf2_b, 1048576);

  // stage 1: rmsnorm + causal dwconv -> y (bf16); x1 = y@Wpw^T + b + x -> d_out
  rms_reduce<<<dim3(T_), 256, 0, stream>>>(x, inv);
  dwconv_k<<<dim3(T_), 256, 0, stream>>>(x, inv, cdw, cdb, cng, zbuf);
  gemm_k<0><<<dim3(8, 128), 256, 0, stream>>>(zbuf, wpw_b, cpb, x, out, nullptr, T_, 1024, 1024);

  // stage 2: z1 = rmsnorm(x1)*g (bf16); hg = z1 @ Wgru^T (bf16); scan; x2 = h + x1 in-place
  rms_scale<<<dim3(T_), 256, 0, stream>>>(out, gng, zbuf);
  gemm_k<3><<<dim3(16, 128), 256, 0, stream>>>(zbuf, wgr_b, nullptr, nullptr, nullptr, hg, T_, 2048, 1024);
  scan_p1<<<dim3(512), 256, 0, stream>>>(hg, Ag, Bg);
  scan_p2<<<dim3(16), 256, 0, stream>>>(Ag, Bg, Pre);
  scan_p3<<<dim3(512), 256, 0, stream>>>(hg, Pre, out, nh);

  // stage 3: z2 = rmsnorm(x2)*g (bf16); h1 = gelu(z2@W1^T + b1) bf16; out = h1@W2^T + b2 + x2
  rms_scale<<<dim3(T_), 256, 0, stream>>>(out, fng, zbuf);
  gemm_k<2><<<dim3(32, 128), 256, 0, stream>>>(zbuf, wf1_b, fb1, nullptr, nullptr, h1, T_, 4096, 1024);
  gemm_k<0><<<dim3(8, 128), 256, 0, stream>>>(h1, wf2_b, fb2, out, out, nullptr, T_, 1024, 4096);
}

// Round 4
// 733.055 us; speedup vs baseline: 1.2968x; 1.1432x over previous
//
#include <hip/hip_runtime.h>

typedef __attribute__((ext_vector_type(8))) short short8;
typedef __attribute__((ext_vector_type(4))) float floatx4;

#define D_   1024
#define L_   4096
#define B_   4
#define T_   16384
#define NCH  32     // scan chunks per sequence
#define CHL  128    // scan chunk length

__device__ __forceinline__ ushort f2bf(float f) {
  unsigned u = __float_as_uint(f);
  u += 0x7fffu + ((u >> 16) & 1u);   // round-to-nearest-even
  return (ushort)(u >> 16);
}
__device__ __forceinline__ float bf2f(ushort u) {
  return __uint_as_float(((unsigned)u) << 16);
}

// async global->LDS, 16B per lane. LDS dest MUST be wave-uniform base + lane*16.
__device__ __forceinline__ void gl2lds(const ushort* g, ushort* l) {
  __builtin_amdgcn_global_load_lds(
      (const __attribute__((address_space(1))) unsigned int*)g,
      (__attribute__((address_space(3))) unsigned int*)l, 16, 0, 0);
}

// ---------------- weight fp32 -> bf16 ----------------
__global__ __launch_bounds__(256) void cvt_bf(const float* __restrict__ s,
                                              ushort* __restrict__ d, int n4) {
  int i = blockIdx.x * 256 + threadIdx.x;
  if (i >= n4) return;
  float4 v = ((const float4*)s)[i];
  ushort4 o;
  o.x = f2bf(v.x); o.y = f2bf(v.y); o.z = f2bf(v.z); o.w = f2bf(v.w);
  ((ushort4*)d)[i] = o;
}

// ---------------- fused rmsnorm + gamma-scale -> bf16 (stages 2,3) ----------------
__global__ __launch_bounds__(256) void rms_scale(const float* __restrict__ x,
                                                 const float* __restrict__ g,
                                                 ushort* __restrict__ z) {
  int t = blockIdx.x;
  float4 v = ((const float4*)(x + (size_t)t * D_))[threadIdx.x];
  float s = v.x * v.x + v.y * v.y + v.z * v.z + v.w * v.w;
#pragma unroll
  for (int off = 32; off > 0; off >>= 1) s += __shfl_xor(s, off, 64);
  __shared__ float red[4];
  if ((threadIdx.x & 63) == 0) red[threadIdx.x >> 6] = s;
  __syncthreads();
  float iv = 32.0f / fmaxf(sqrtf(red[0] + red[1] + red[2] + red[3]), 1e-12f);
  float4 gg = ((const float4*)g)[threadIdx.x];
  ushort4 o;
  o.x = f2bf(v.x * iv * (gg.x + 1.f));
  o.y = f2bf(v.y * iv * (gg.y + 1.f));
  o.z = f2bf(v.z * iv * (gg.z + 1.f));
  o.w = f2bf(v.w * iv * (gg.w + 1.f));
  ((ushort4*)(z + (size_t)t * D_))[threadIdx.x] = o;
}

// ---------------- fused rmsnorm (3 norms in-block) + causal dwconv (K=3) ----------------
__global__ __launch_bounds__(256) void dwconv_k(const float* __restrict__ x,
                                                const float* __restrict__ wdw,
                                                const float* __restrict__ bdw,
                                                const float* __restrict__ gm,
                                                ushort* __restrict__ y) {
  int t = blockIdx.x;
  int c4 = threadIdx.x << 2;
  int l = t & (L_ - 1);
  const float* p0 = x + (size_t)t * D_ + c4;
  float4 v0 = *(const float4*)p0;
  float4 v1 = {0.f, 0.f, 0.f, 0.f}, v2 = {0.f, 0.f, 0.f, 0.f};
  if (l >= 1) v1 = *(const float4*)(p0 - D_);
  if (l >= 2) v2 = *(const float4*)(p0 - 2 * D_);
  float s0 = v0.x * v0.x + v0.y * v0.y + v0.z * v0.z + v0.w * v0.w;
  float s1 = v1.x * v1.x + v1.y * v1.y + v1.z * v1.z + v1.w * v1.w;
  float s2 = v2.x * v2.x + v2.y * v2.y + v2.z * v2.z + v2.w * v2.w;
#pragma unroll
  for (int off = 32; off > 0; off >>= 1) {
    s0 += __shfl_xor(s0, off, 64);
    s1 += __shfl_xor(s1, off, 64);
    s2 += __shfl_xor(s2, off, 64);
  }
  __shared__ float r0[4], r1[4], r2[4];
  if ((threadIdx.x & 63) == 0) {
    int w = threadIdx.x >> 6;
    r0[w] = s0; r1[w] = s1; r2[w] = s2;
  }
  __syncthreads();
  float i0 = 32.0f / fmaxf(sqrtf(r0[0] + r0[1] + r0[2] + r0[3]), 1e-12f);
  float i1 = 32.0f / fmaxf(sqrtf(r1[0] + r1[1] + r1[2] + r1[3]), 1e-12f);
  float i2 = 32.0f / fmaxf(sqrtf(r2[0] + r2[1] + r2[2] + r2[3]), 1e-12f);
  float a0[4] = {v0.x, v0.y, v0.z, v0.w};
  float a1[4] = {v1.x, v1.y, v1.z, v1.w};
  float a2[4] = {v2.x, v2.y, v2.z, v2.w};
  ushort r[4];
#pragma unroll
  for (int j = 0; j < 4; ++j) {
    int d = c4 + j;
    float w0 = wdw[d * 3 + 0], w1 = wdw[d * 3 + 1], w2 = wdw[d * 3 + 2];
    float s = w2 * a0[j] * i0 + w1 * a1[j] * i1 + w0 * a2[j] * i2;
    s = s * (gm[d] + 1.0f) + bdw[d];
    r[j] = f2bf(s);
  }
  ushort4 o; o.x = r[0]; o.y = r[1]; o.z = r[2]; o.w = r[3];
  *(ushort4*)(y + (size_t)t * D_ + c4) = o;
}

// ---------------- bf16 MFMA GEMM (m97 pattern + XCD-aware swizzle) ----------------
// A: [M][K] bf16 row-major, W: [N][K] bf16 row-major. C = A @ W^T.
// MODE 0: outF = acc + bias + resid (fp32).
// MODE 2: outB = bf16(gelu_tanh(acc + bias)).
// MODE 4: minGRU gate transform: col<1024 -> ghid = g(acc); col>=1024 -> a = sigmoid(-acc).
template <int MODE>
__global__ __launch_bounds__(256, 2) void gemm_k(
    const ushort* __restrict__ A, const ushort* __restrict__ W,
    const float* __restrict__ bias, const float* __restrict__ resid,
    float* __restrict__ outF, ushort* __restrict__ outB, int M, int N, int K) {
  __shared__ ushort lA[128 * 32];
  __shared__ ushort lB[128 * 32];
  int tid = threadIdx.x;

  // --- XCD-aware remap (requires gridDim.y % 8 == 0, nx a power of 2) ---
  int nx = gridDim.x;
  int lxs = 31 - __clz(nx);                // log2(nx)
  int lin = blockIdx.x + blockIdx.y * nx;  // dispatch-order linear id
  int c = lin & 7, q = lin >> 3;
  int by = (c * (gridDim.y >> 3)) + (q >> lxs);
  int bx = q & (nx - 1);
  int bm = by * 128;
  int bn = bx * 128;

  int wave = tid >> 6, lane = tid & 63;
  int wm = (wave & 1) << 6, wn = (wave >> 1) << 6;
  int row = tid >> 2, kc = (tid & 3) << 3;   // each thread DMAs 16B; 256 thr = 64 rows
  const ushort* pa0 = A + (size_t)(bm + row) * K + kc;
  const ushort* pa1 = pa0 + (size_t)64 * K;
  const ushort* pb0 = W + (size_t)(bn + row) * K + kc;
  const ushort* pb1 = pb0 + (size_t)64 * K;
  ushort* dA0 = lA + tid * 8;           // == (row*32 + kc), lane-contiguous
  ushort* dA1 = dA0 + 64 * 32;
  ushort* dB0 = lB + tid * 8;
  ushort* dB1 = dB0 + 64 * 32;
  int fr = lane & 15, fq = lane >> 4;

  floatx4 acc[4][4];
#pragma unroll
  for (int i = 0; i < 4; ++i)
#pragma unroll
    for (int j = 0; j < 4; ++j) acc[i][j] = {0.f, 0.f, 0.f, 0.f};

  for (int k0 = 0; k0 < K; k0 += 32) {
    __syncthreads();                    // previous tile fully consumed
    gl2lds(pa0 + k0, dA0);
    gl2lds(pa1 + k0, dA1);
    gl2lds(pb0 + k0, dB0);
    gl2lds(pb1 + k0, dB1);
    __syncthreads();                    // vmcnt(0) drained -> tile ready
    short8 af[4], bfr[4];
#pragma unroll
    for (int i = 0; i < 4; ++i)
      af[i] = *(const short8*)(lA + (wm + i * 16 + fr) * 32 + fq * 8);
#pragma unroll
    for (int j = 0; j < 4; ++j)
      bfr[j] = *(const short8*)(lB + (wn + j * 16 + fr) * 32 + fq * 8);
#pragma unroll
    for (int i = 0; i < 4; ++i)
#pragma unroll
      for (int j = 0; j < 4; ++j)
        acc[i][j] = __builtin_amdgcn_mfma_f32_16x16x32_bf16(af[i], bfr[j], acc[i][j], 0, 0, 0);
  }

#pragma unroll
  for (int i = 0; i < 4; ++i) {
#pragma unroll
    for (int j = 0; j < 4; ++j) {
      int colg = bn + wn + j * 16 + fr;
      float bv = (MODE == 4) ? 0.f : bias[colg];
#pragma unroll
      for (int r = 0; r < 4; ++r) {
        int rowg = bm + wm + i * 16 + fq * 4 + r;
        size_t idx = (size_t)rowg * N + colg;
        float v = acc[i][j][r];
        if (MODE == 0) {
          outF[idx] = v + bv + resid[idx];
        } else if (MODE == 2) {
          v += bv;
          // gelu(x) ~= x * sigmoid(1.5957691(x + 0.044715 x^3)); maxerr ~1e-3
          float u = 1.5957691216f * (v + 0.044715f * v * v * v);
          v = v / (1.f + __expf(-u));
          outB[idx] = f2bf(v);
        } else {  // MODE 4
          float o;
          if (colg < 1024)
            o = (v >= 0.f) ? (v + 0.5f) : (1.f / (1.f + __expf(-v)));  // g(hidden)
          else
            o = 1.f / (1.f + __expf(v));                               // a = sigmoid(-gate)
          outB[idx] = f2bf(o);
        }
      }
    }
  }
}

// ---------------- minGRU linear-space chunked scan (pure FMA now) ----------------
// hg layout: [T][2048], col<1024: ghid, col>=1024: a. h_t = a h_{t-1} + (1-a) ghid.
__global__ __launch_bounds__(256) void scan_p1(const ushort* __restrict__ hg,
                                               float* __restrict__ Ag,
                                               float* __restrict__ Bg) {
  int blk = blockIdx.x;
  int dt = blk & 3, ch = (blk >> 2) & 31, b = blk >> 7;
  int d = (dt << 8) + threadIdx.x;
  const ushort* p = hg + (size_t)(b * L_ + ch * CHL) * 2048 + d;
  float A = 1.f, Bv = 0.f;
  for (int s = 0; s < CHL; ++s) {
    float g = bf2f(p[0]), a = bf2f(p[1024]);
    p += 2048;
    A *= a;
    Bv = fmaf(a, Bv, (1.f - a) * g);
  }
  size_t o = (size_t)((b * NCH + ch) * D_) + d;
  Ag[o] = A; Bg[o] = Bv;
}

__global__ __launch_bounds__(256) void scan_p2(const float* __restrict__ Ag,
                                               const float* __restrict__ Bg,
                                               float* __restrict__ Pre) {
  int dt = blockIdx.x & 3, b = blockIdx.x >> 2;
  int d = (dt << 8) + threadIdx.x;
  float h = 0.f;
  for (int c = 0; c < NCH; ++c) {
    size_t i = (size_t)((b * NCH + c) * D_) + d;
    Pre[i] = h;
    h = fmaf(Ag[i], h, Bg[i]);
  }
}

__global__ __launch_bounds__(256) void scan_p3(const ushort* __restrict__ hg,
                                               const float* __restrict__ Pre,
                                               float* __restrict__ xio,
                                               float* __restrict__ nh) {
  int blk = blockIdx.x;
  int dt = blk & 3, ch = (blk >> 2) & 31, b = blk >> 7;
  int d = (dt << 8) + threadIdx.x;
  const ushort* p = hg + (size_t)(b * L_ + ch * CHL) * 2048 + d;
  float* q = xio + (size_t)(b * L_ + ch * CHL) * D_ + d;
  float h = Pre[(size_t)((b * NCH + ch) * D_) + d];
  for (int s = 0; s < CHL; ++s) {
    float g = bf2f(p[0]), a = bf2f(p[1024]);
    p += 2048;
    h = fmaf(a, h, (1.f - a) * g);
    *q = h + *q;
    q += D_;
  }
  if (ch == NCH - 1) nh[(b << 10) + d] = h;
}

// ---------------- launcher ----------------
extern "C" void kernel_launch(void* const* d_in, const int* in_sizes, int n_in,
                              void* d_out, int out_size, void* d_ws, size_t ws_size,
                              hipStream_t stream) {
  const float* x   = (const float*)d_in[0];
  const float* cdw = (const float*)d_in[1];
  const float* cdb = (const float*)d_in[2];
  const float* cpw = (const float*)d_in[3];
  const float* cpb = (const float*)d_in[4];
  const float* cng = (const float*)d_in[5];
  const float* gng = (const float*)d_in[6];
  const float* gw  = (const float*)d_in[7];
  const float* fng = (const float*)d_in[8];
  const float* fw1 = (const float*)d_in[9];
  const float* fb1 = (const float*)d_in[10];
  const float* fw2 = (const float*)d_in[11];
  const float* fb2 = (const float*)d_in[12];
  float* out = (float*)d_out;
  char* ws = (char*)d_ws;

  // workspace layout (bytes)
  ushort* wpw_b = (ushort*)(ws + 0);          //  2 MiB
  ushort* wgr_b = (ushort*)(ws + 2097152);    //  4 MiB
  ushort* wf1_b = (ushort*)(ws + 6291456);    //  8 MiB
  ushort* wf2_b = (ushort*)(ws + 14680064);   //  8 MiB
  float*  Ag    = (float*) (ws + 23134208);   // 512 KiB
  float*  Bg    = (float*) (ws + 23658496);   // 512 KiB
  float*  Pre   = (float*) (ws + 24182784);   // 512 KiB
  ushort* zbuf  = (ushort*)(ws + 24707072);   // 32 MiB (y / z1 / z2, reused)
  ushort* hg    = (ushort*)(ws + 58261504);   // 64 MiB bf16 [T][2048] (ghid | a)
  ushort* h1    = (ushort*)(ws + 58261504);   // 128 MiB bf16 [T][4096] (overlays hg; hg dead)
  float*  nh    = out + (size_t)T_ * D_;      // next_hidden tail of d_out

  // weights -> bf16
  cvt_bf<<<dim3(1024), 256, 0, stream>>>(cpw, wpw_b, 262144);
  cvt_bf<<<dim3(2048), 256, 0, stream>>>(gw,  wgr_b, 524288);
  cvt_bf<<<dim3(4096), 256, 0, stream>>>(fw1, wf1_b, 1048576);
  cvt_bf<<<dim3(4096), 256, 0, stream>>>(fw2, wf2_b, 1048576);

  // stage 1: fused rmsnorm + causal dwconv -> y (bf16); x1 = y@Wpw^T + b + x -> d_out
  dwconv_k<<<dim3(T_), 256, 0, stream>>>(x, cdw, cdb, cng, zbuf);
  gemm_k<0><<<dim3(8, 128), 256, 0, stream>>>(zbuf, wpw_b, cpb, x, out, nullptr, T_, 1024, 1024);

  // stage 2: z1 = rmsnorm(x1)*g (bf16); hg = gate-transform(z1 @ Wgru^T); scan; x2 = h + x1
  rms_scale<<<dim3(T_), 256, 0, stream>>>(out, gng, zbuf);
  gemm_k<4><<<dim3(16, 128), 256, 0, stream>>>(zbuf, wgr_b, nullptr, nullptr, nullptr, hg, T_, 2048, 1024);
  scan_p1<<<dim3(512), 256, 0, stream>>>(hg, Ag, Bg);
  scan_p2<<<dim3(16), 256, 0, stream>>>(Ag, Bg, Pre);
  scan_p3<<<dim3(512), 256, 0, stream>>>(hg, Pre, out, nh);

  // stage 3: z2 = rmsnorm(x2)*g (bf16); h1 = gelu(z2@W1^T + b1) bf16; out = h1@W2^T + b2 + x2
  rms_scale<<<dim3(T_), 256, 0, stream>>>(out, fng, zbuf);
  gemm_k<2><<<dim3(32, 128), 256, 0, stream>>>(zbuf, wf1_b, fb1, nullptr, nullptr, h1, T_, 4096, 1024);
  gemm_k<0><<<dim3(8, 128), 256, 0, stream>>>(h1, wf2_b, fb2, out, out, nullptr, T_, 1024, 4096);
}